// Round 4
// baseline (2356.585 us; speedup 1.0000x reference)
//
#include <hip/hip_runtime.h>
#include <hip/hip_cooperative_groups.h>
#include <math.h>

namespace cgx = cooperative_groups;

#define MAX_ITER 20
#define EPS_W 1e-3f
#define CLAMP_MIN 1e-4f
#define CLAMP_MAX 1e4f

#define E 16
#define CGBLK 256
#define CHUNK (E * CGBLK)  // 4096 elements per block

__device__ __forceinline__ float sp_w(float u) {
    float sp = fmaxf(u, 0.f) + log1pf(expf(-fabsf(u)));
    float w = sp + EPS_W;
    return fminf(fmaxf(w, CLAMP_MIN), CLAMP_MAX);
}
__device__ __forceinline__ float nn(float x) { return (x == x) ? x : 0.f; }

__device__ __forceinline__ float agent_ld(const float* p) {
    return __hip_atomic_load(p, __ATOMIC_RELAXED, __HIP_MEMORY_SCOPE_AGENT);
}
__device__ __forceinline__ void agent_st(float* p, float v) {
    __hip_atomic_store(p, v, __ATOMIC_RELAXED, __HIP_MEMORY_SCOPE_AGENT);
}

// result valid on threadIdx.x == 0 only; block must be 256 threads (4 waves)
__device__ __forceinline__ float blockReduceSum(float v) {
    #pragma unroll
    for (int off = 32; off > 0; off >>= 1) v += __shfl_down(v, off, 64);
    __shared__ float smem[4];
    int lane = threadIdx.x & 63, wid = threadIdx.x >> 6;
    if (lane == 0) smem[wid] = v;
    __syncthreads();
    float r = 0.f;
    if (threadIdx.x == 0) r = smem[0] + smem[1] + smem[2] + smem[3];
    return r;
}

__global__ __launch_bounds__(256) void k_scatter(const int* __restrict__ idx,
                                                 int* __restrict__ pos, int K) {
    int k = blockIdx.x * 256 + threadIdx.x;
    if (k < K) pos[idx[k]] = k;
}

__global__ __launch_bounds__(256) void k_w(const float* __restrict__ u,
                                           float* __restrict__ w, int total4) {
    int t = blockIdx.x * 256 + threadIdx.x;
    if (t >= total4) return;
    float4 uu = reinterpret_cast<const float4*>(u)[t];
    float4 ww;
    ww.x = sp_w(uu.x); ww.y = sp_w(uu.y); ww.z = sp_w(uu.z); ww.w = sp_w(uu.w);
    reinterpret_cast<float4*>(w)[t] = ww;
}

// init (4 elems/thread): rg=rhs, dg, cl arrays + rs0 reduction. Reads precomputed w.
__global__ __launch_bounds__(256) void k_init(const int* __restrict__ idx,
                                              const float* __restrict__ w_all,
                                              const float* __restrict__ x,
                                              float* __restrict__ rg,
                                              float* __restrict__ dg,
                                              float* __restrict__ cl,
                                              float* __restrict__ rs_arr,
                                              int n, int K) {
    int t = blockIdx.x * 256 + threadIdx.x;
    int g = t * 4;                 // flat over B*K
    int b = g / K;
    int k = g - b * K;             // K % 1024 == 0 -> 4 elems same batch
    int m = n - 1;
    const float* wb = w_all + (size_t)b * m;
    const float* xb = x + (size_t)b * n;
    int4 i4 = reinterpret_cast<const int4*>(idx)[k / 4];
    int jj[6];
    jj[0] = (k > 0) ? idx[k - 1] : -1000000;
    jj[1] = i4.x; jj[2] = i4.y; jj[3] = i4.z; jj[4] = i4.w;
    jj[5] = (k + 4 < K) ? idx[k + 4] : -1000000;
    float rh[4], dgv[4], clv[4];
    float s0 = 0.f;
    #pragma unroll
    for (int q = 0; q < 4; ++q) {
        int j = jj[q + 1];
        bool la = (jj[q] == j - 1);
        bool ra = (jj[q + 2] == j + 1);
        float wl = 0.f, wr = 0.f;
        if (j >= 1)     { float w = wb[j - 1]; wl = w * w; }
        if (j <= n - 2) { float w = wb[j];     wr = w * w; }
        float rhs = 0.f;
        if (j >= 1 && !la)     rhs += wl * nn(xb[j - 1]);
        if (j <= n - 2 && !ra) rhs += wr * nn(xb[j + 1]);
        rh[q] = rhs; dgv[q] = wl + wr; clv[q] = la ? wl : 0.f;
        s0 += rhs * rhs;
    }
    reinterpret_cast<float4*>(rg)[t] = make_float4(rh[0], rh[1], rh[2], rh[3]);
    reinterpret_cast<float4*>(dg)[t] = make_float4(dgv[0], dgv[1], dgv[2], dgv[3]);
    reinterpret_cast<float4*>(cl)[t] = make_float4(clv[0], clv[1], clv[2], clv[3]);
    float s = blockReduceSum(s0);
    if (threadIdx.x == 0) atomicAdd(&rs_arr[b], s);
}

// Persistent cooperative CG: state in registers, loaded from rg/dg/cl.
__global__ __launch_bounds__(CGBLK, 2) void k_cg_pers(
        const float* __restrict__ rg_in, const float* __restrict__ dg_in,
        const float* __restrict__ cl_in, float* __restrict__ v_out,
        float* __restrict__ rs_arr, float* __restrict__ pkp_arr,
        float* __restrict__ pbl, float* __restrict__ pbr,   // [2*grid]
        float* __restrict__ rbl, float* __restrict__ rbr,   // [grid]
        int K, int B, int total) {
    cgx::grid_group grid = cgx::this_grid();
    const int blk = blockIdx.x, tid = threadIdx.x, nblk = gridDim.x;
    const int bpb = K / CHUNK;
    const int b = blk / bpb;
    const bool first_blk = (blk % bpb) == 0;
    const bool last_blk  = (blk % bpb) == bpb - 1;
    const size_t g0 = (size_t)blk * CHUNK + (size_t)tid * E;

    float vv[E], rcg[E], p[E], kp[E], dgr[E], clr[E + 1];
    #pragma unroll
    for (int q4 = 0; q4 < E / 4; ++q4) {
        float4 r = reinterpret_cast<const float4*>(rg_in)[g0 / 4 + q4];
        float4 d = reinterpret_cast<const float4*>(dg_in)[g0 / 4 + q4];
        float4 c = reinterpret_cast<const float4*>(cl_in)[g0 / 4 + q4];
        rcg[4 * q4 + 0] = r.x; rcg[4 * q4 + 1] = r.y; rcg[4 * q4 + 2] = r.z; rcg[4 * q4 + 3] = r.w;
        dgr[4 * q4 + 0] = d.x; dgr[4 * q4 + 1] = d.y; dgr[4 * q4 + 2] = d.z; dgr[4 * q4 + 3] = d.w;
        clr[4 * q4 + 0] = c.x; clr[4 * q4 + 1] = c.y; clr[4 * q4 + 2] = c.z; clr[4 * q4 + 3] = c.w;
    }
    clr[E] = (g0 + E < (size_t)total) ? cl_in[g0 + E] : 0.f;  // cross-batch hits cl[0]==0
    #pragma unroll
    for (int q = 0; q < E; ++q) { vv[q] = 0.f; p[q] = rcg[q]; kp[q] = 0.f; }

    if (tid == 0)         { agent_st(&rbl[blk], rcg[0]);     agent_st(&pbl[blk], p[0]); }
    if (tid == CGBLK - 1) { agent_st(&rbr[blk], rcg[E - 1]); agent_st(&pbr[blk], p[E - 1]); }
    grid.sync();

    __shared__ float sLa[CGBLK], sRa[CGBLK];

    for (int it = 0; it < MAX_ITER; ++it) {
        // ---- phase A: p update, halos, Kp, p.Kp ----
        float beta = 0.f;
        if (it > 0)
            beta = agent_ld(&rs_arr[it * B + b]) /
                   (agent_ld(&rs_arr[(it - 1) * B + b]) + 1e-30f);
        #pragma unroll
        for (int q = 0; q < E; ++q) p[q] = rcg[q] + beta * p[q];
        sLa[tid] = p[0]; sRa[tid] = p[E - 1];
        __syncthreads();
        int rslot = (it & 1) * nblk, wslot = ((it + 1) & 1) * nblk;
        float pl, pr;
        if (tid > 0) pl = sRa[tid - 1];
        else pl = first_blk ? 0.f
                            : (agent_ld(&rbr[blk - 1]) + beta * agent_ld(&pbr[rslot + blk - 1]));
        if (tid < CGBLK - 1) pr = sLa[tid + 1];
        else pr = last_blk ? 0.f
                           : (agent_ld(&rbl[blk + 1]) + beta * agent_ld(&pbl[rslot + blk + 1]));
        if (tid == 0)         agent_st(&pbl[wslot + blk], p[0]);
        if (tid == CGBLK - 1) agent_st(&pbr[wslot + blk], p[E - 1]);
        float dot = 0.f;
        #pragma unroll
        for (int q = 0; q < E; ++q) {
            float pm = (q == 0) ? pl : p[q - 1];
            float pp = (q == E - 1) ? pr : p[q + 1];
            kp[q] = dgr[q] * p[q] - clr[q] * pm - clr[q + 1] * pp;
            dot += p[q] * kp[q];
        }
        float d = blockReduceSum(dot);
        if (tid == 0) atomicAdd(&pkp_arr[it * B + b], d);
        grid.sync();

        // ---- phase B: alpha, v/rcg update, ||r||^2 ----
        float alpha = agent_ld(&rs_arr[it * B + b]) /
                      (agent_ld(&pkp_arr[it * B + b]) + 1e-30f);
        float dot2 = 0.f;
        #pragma unroll
        for (int q = 0; q < E; ++q) {
            vv[q] += alpha * p[q];
            rcg[q] -= alpha * kp[q];
            dot2 += rcg[q] * rcg[q];
        }
        float d2 = blockReduceSum(dot2);
        if (tid == 0) {
            atomicAdd(&rs_arr[(it + 1) * B + b], d2);
            agent_st(&rbl[blk], rcg[0]);
        }
        if (tid == CGBLK - 1) agent_st(&rbr[blk], rcg[E - 1]);
        grid.sync();
    }

    #pragma unroll
    for (int q4 = 0; q4 < E / 4; ++q4)
        reinterpret_cast<float4*>(v_out)[g0 / 4 + q4] =
            make_float4(vv[4 * q4], vv[4 * q4 + 1], vv[4 * q4 + 2], vv[4 * q4 + 3]);
}

// ---- fallback multi-kernel CG (round-2, known good) ----
__global__ __launch_bounds__(256) void k_cg_a(const float* __restrict__ rg,
                                              const float* __restrict__ p_old,
                                              float* __restrict__ p_new,
                                              float* __restrict__ kp,
                                              const float* __restrict__ dg,
                                              const float* __restrict__ cl,
                                              const float* __restrict__ rs_arr,
                                              float* __restrict__ pkp_arr,
                                              int iter, int B, int K) {
    int t = blockIdx.x * 256 + threadIdx.x;
    int g = t * 4;
    int total = B * K;
    int b = g / K;
    float beta = (iter == 0) ? 0.f
               : rs_arr[iter * B + b] / (rs_arr[(iter - 1) * B + b] + 1e-30f);
    float4 rc = reinterpret_cast<const float4*>(rg)[t];
    float4 po = reinterpret_cast<const float4*>(p_old)[t];
    float4 dd = reinterpret_cast<const float4*>(dg)[t];
    float4 cc = reinterpret_cast<const float4*>(cl)[t];
    float rcm = (g > 0) ? rg[g - 1] : 0.f;
    float pom = (g > 0) ? p_old[g - 1] : 0.f;
    bool tail = (g + 4 < total);
    float rcp = tail ? rg[g + 4] : 0.f;
    float pop = tail ? p_old[g + 4] : 0.f;
    float ccp = tail ? cl[g + 4] : 0.f;
    float pn[6];
    pn[0] = rcm + beta * pom;
    pn[1] = rc.x + beta * po.x;
    pn[2] = rc.y + beta * po.y;
    pn[3] = rc.z + beta * po.z;
    pn[4] = rc.w + beta * po.w;
    pn[5] = rcp + beta * pop;
    float c[5] = {cc.x, cc.y, cc.z, cc.w, ccp};
    float d4[4] = {dd.x, dd.y, dd.z, dd.w};
    float kv[4];
    float dot = 0.f;
    #pragma unroll
    for (int i = 0; i < 4; ++i) {
        kv[i] = d4[i] * pn[i + 1] - c[i] * pn[i] - c[i + 1] * pn[i + 2];
        dot += pn[i + 1] * kv[i];
    }
    reinterpret_cast<float4*>(p_new)[t] = make_float4(pn[1], pn[2], pn[3], pn[4]);
    reinterpret_cast<float4*>(kp)[t]    = make_float4(kv[0], kv[1], kv[2], kv[3]);
    float s = blockReduceSum(dot);
    if (threadIdx.x == 0) atomicAdd(&pkp_arr[iter * B + b], s);
}

__global__ __launch_bounds__(256) void k_cg_b(float* __restrict__ v,
                                              float* __restrict__ rg,
                                              const float* __restrict__ p_new,
                                              const float* __restrict__ kp,
                                              float* __restrict__ rs_arr,
                                              const float* __restrict__ pkp_arr,
                                              int iter, int B, int K) {
    int t = blockIdx.x * 256 + threadIdx.x;
    int g = t * 4;
    int b = g / K;
    float alpha = rs_arr[iter * B + b] / (pkp_arr[iter * B + b] + 1e-30f);
    float4 pv = reinterpret_cast<const float4*>(p_new)[t];
    float4 kv = reinterpret_cast<const float4*>(kp)[t];
    float4 vv = reinterpret_cast<float4*>(v)[t];
    float4 rv = reinterpret_cast<float4*>(rg)[t];
    vv.x += alpha * pv.x; vv.y += alpha * pv.y; vv.z += alpha * pv.z; vv.w += alpha * pv.w;
    rv.x -= alpha * kv.x; rv.y -= alpha * kv.y; rv.z -= alpha * kv.z; rv.w -= alpha * kv.w;
    reinterpret_cast<float4*>(v)[t]  = vv;
    reinterpret_cast<float4*>(rg)[t] = rv;
    float dot = rv.x * rv.x + rv.y * rv.y + rv.z * rv.z + rv.w * rv.w;
    float s = blockReduceSum(dot);
    if (threadIdx.x == 0) atomicAdd(&rs_arr[(iter + 1) * B + b], s);
}

// final: r = D(x_known + scatter(v)), phi = sum w^2 r^2
__global__ __launch_bounds__(256) void k_final(const float* __restrict__ x,
                                               const float* __restrict__ w_out,
                                               const int* __restrict__ pos,
                                               const float* __restrict__ v,
                                               float* __restrict__ r_out,
                                               float* __restrict__ phi,
                                               int n, int K) {
    int m = n - 1;
    int b = blockIdx.y;
    int i0 = (blockIdx.x * 256 + threadIdx.x) * 4;
    const float* xb = x + (size_t)b * n;
    const float* wb = w_out + (size_t)b * m;
    const float* vb = v + (size_t)b * K;
    float* rb = r_out + (size_t)b * m;
    float sv[5];
    #pragma unroll
    for (int q = 0; q < 5; ++q) {
        int i = i0 + q;
        if (i <= m) {
            int p = pos[i];
            sv[q] = (p >= 0) ? vb[p] : nn(xb[i]);
        } else sv[q] = 0.f;
    }
    float acc = 0.f;
    #pragma unroll
    for (int q = 0; q < 4; ++q) {
        int i = i0 + q;
        if (i < m) {
            float r = sv[q + 1] - sv[q];
            rb[i] = r;
            float w = wb[i];
            acc += w * w * r * r;
        }
    }
    float s = blockReduceSum(acc);
    if (threadIdx.x == 0) atomicAdd(&phi[b], s);
}

extern "C" void kernel_launch(void* const* d_in, const int* in_sizes, int n_in,
                              void* d_out, int out_size, void* d_ws, size_t ws_size,
                              hipStream_t stream) {
    const float* u  = (const float*)d_in[0];  // [B, n-1]
    const float* x  = (const float*)d_in[1];  // [B, n]
    const int* idx  = (const int*)d_in[2];    // [K]

    const int B = 16;
    const int n = in_sizes[1] / B;   // 262144
    const int m = n - 1;             // 262143
    const int K = in_sizes[2];       // 131072
    const int NK = B * K;            // 2097152
    const int GRID = NK / CHUNK;     // 512 blocks

    float* out   = (float*)d_out;
    float* phi   = out;                         // [B]
    float* v_out = out + B;                     // [B,K]
    float* r_out = v_out + (size_t)B * K;       // [B,m]
    float* w_out = r_out + (size_t)B * m;       // [B,m]

    char* ws = (char*)d_ws;
    float* rg  = (float*)ws;      ws += sizeof(float) * (size_t)NK;
    float* dg  = (float*)ws;      ws += sizeof(float) * (size_t)NK;
    float* cl  = (float*)ws;      ws += sizeof(float) * (size_t)NK;
    float* p0f = (float*)ws;      ws += sizeof(float) * (size_t)NK;
    float* p1f = (float*)ws;      ws += sizeof(float) * (size_t)NK;
    float* kpf = (float*)ws;      ws += sizeof(float) * (size_t)NK;
    float* vf  = (float*)ws;      ws += sizeof(float) * (size_t)NK;
    float* rs_arr  = (float*)ws;  ws += sizeof(float) * (MAX_ITER + 1) * B;
    float* pkp_arr = (float*)ws;  ws += sizeof(float) * MAX_ITER * B;
    float* pbl = (float*)ws;      ws += sizeof(float) * 2 * GRID;
    float* pbr = (float*)ws;      ws += sizeof(float) * 2 * GRID;
    float* rbl = (float*)ws;      ws += sizeof(float) * GRID;
    float* rbr = (float*)ws;      ws += sizeof(float) * GRID;
    int*   pos = (int*)ws;        ws += sizeof(int) * (size_t)n;

    hipMemsetAsync(rs_arr, 0, sizeof(float) * ((MAX_ITER + 1) * B + MAX_ITER * B), stream);
    hipMemsetAsync(pos, 0xFF, sizeof(int) * (size_t)n, stream);  // -1
    hipMemsetAsync(phi, 0, sizeof(float) * B, stream);

    k_scatter<<<(K + 255) / 256, 256, 0, stream>>>(idx, pos, K);

    int tot4w = (B * m) / 4;
    k_w<<<(tot4w + 255) / 256, 256, 0, stream>>>(u, w_out, tot4w);

    k_init<<<NK / 1024, 256, 0, stream>>>(idx, w_out, x, rg, dg, cl, rs_arr, n, K);

    int K_ = K, B_ = B, total_ = NK;
    void* args[] = {(void*)&rg, (void*)&dg, (void*)&cl, (void*)&v_out,
                    (void*)&rs_arr, (void*)&pkp_arr,
                    (void*)&pbl, (void*)&pbr, (void*)&rbl, (void*)&rbr,
                    (void*)&K_, (void*)&B_, (void*)&total_};
    hipError_t cerr = hipLaunchCooperativeKernel((const void*)k_cg_pers, dim3(GRID),
                                                 dim3(CGBLK), args, 0, stream);
    const float* vsrc = v_out;
    if (cerr != hipSuccess) {
        // fallback: known-good multi-kernel CG loop
        hipMemsetAsync(vf, 0, sizeof(float) * (size_t)NK, stream);
        for (int it = 0; it < MAX_ITER; ++it) {
            const float* po = (it == 0) ? rg : ((it & 1) ? p0f : p1f);
            float* pnw = (it & 1) ? p1f : p0f;
            k_cg_a<<<NK / 1024, 256, 0, stream>>>(rg, po, pnw, kpf, dg, cl,
                                                  rs_arr, pkp_arr, it, B, K);
            k_cg_b<<<NK / 1024, 256, 0, stream>>>(vf, rg, pnw, kpf,
                                                  rs_arr, pkp_arr, it, B, K);
        }
        hipMemcpyAsync(v_out, vf, sizeof(float) * (size_t)NK, hipMemcpyDeviceToDevice, stream);
        vsrc = vf;
    }

    k_final<<<dim3((m + 1023) / 1024, B), 256, 0, stream>>>(x, w_out, pos, vsrc, r_out, phi, n, K);
}

// Round 5
// 1375.561 us; speedup vs baseline: 1.7132x; 1.7132x over previous
//
#include <hip/hip_runtime.h>
#include <math.h>

#define MAX_ITER 20
#define EPS_W 1e-3f
#define CLAMP_MIN 1e-4f
#define CLAMP_MAX 1e4f

#define E 16
#define CGBLK 256
#define CHUNK (E * CGBLK)  // 4096 elements per block

__device__ __forceinline__ float sp_w(float u) {
    float sp = fmaxf(u, 0.f) + log1pf(expf(-fabsf(u)));
    float w = sp + EPS_W;
    return fminf(fmaxf(w, CLAMP_MIN), CLAMP_MAX);
}
__device__ __forceinline__ float nn(float x) { return (x == x) ? x : 0.f; }

__device__ __forceinline__ float agent_ld(const float* p) {
    return __hip_atomic_load(p, __ATOMIC_RELAXED, __HIP_MEMORY_SCOPE_AGENT);
}
__device__ __forceinline__ void agent_st(float* p, float v) {
    __hip_atomic_store(p, v, __ATOMIC_RELAXED, __HIP_MEMORY_SCOPE_AGENT);
}

// result valid on threadIdx.x == 0 only; block must be 256 threads (4 waves)
__device__ __forceinline__ float blockReduceSum(float v) {
    #pragma unroll
    for (int off = 32; off > 0; off >>= 1) v += __shfl_down(v, off, 64);
    __shared__ float smem[4];
    int lane = threadIdx.x & 63, wid = threadIdx.x >> 6;
    if (lane == 0) smem[wid] = v;
    __syncthreads();
    float r = 0.f;
    if (threadIdx.x == 0) r = smem[0] + smem[1] + smem[2] + smem[3];
    return r;
}

// Per-batch sense-style barrier: 32 blocks of one batch. arrive[blk] is each
// block's own slot (one 128B line per batch); release[b*32] padded per batch.
// Leader (first block of batch) polls all bpb slots with bpb lanes, then
// publishes gen to release. Release/acquire gives transitive happens-before.
__device__ __forceinline__ void batch_barrier(int* __restrict__ arrive,
                                              int* __restrict__ release,
                                              int blk, int bbase, int bpb,
                                              int relIdx, int gen, bool leader) {
    __syncthreads();
    if (threadIdx.x == 0)
        __hip_atomic_store(&arrive[blk], gen, __ATOMIC_RELEASE, __HIP_MEMORY_SCOPE_AGENT);
    if (leader) {
        if ((int)threadIdx.x < bpb) {
            while (__hip_atomic_load(&arrive[bbase + threadIdx.x], __ATOMIC_ACQUIRE,
                                     __HIP_MEMORY_SCOPE_AGENT) < gen)
                __builtin_amdgcn_s_sleep(1);
        }
        __syncthreads();
        if (threadIdx.x == 0)
            __hip_atomic_store(&release[relIdx], gen, __ATOMIC_RELEASE,
                               __HIP_MEMORY_SCOPE_AGENT);
    } else {
        if (threadIdx.x == 0) {
            while (__hip_atomic_load(&release[relIdx], __ATOMIC_ACQUIRE,
                                     __HIP_MEMORY_SCOPE_AGENT) < gen)
                __builtin_amdgcn_s_sleep(1);
        }
    }
    __syncthreads();
}

__global__ __launch_bounds__(256) void k_scatter(const int* __restrict__ idx,
                                                 int* __restrict__ pos, int K) {
    int k = blockIdx.x * 256 + threadIdx.x;
    if (k < K) pos[idx[k]] = k;
}

__global__ __launch_bounds__(256) void k_w(const float* __restrict__ u,
                                           float* __restrict__ w, int total4) {
    int t = blockIdx.x * 256 + threadIdx.x;
    if (t >= total4) return;
    float4 uu = reinterpret_cast<const float4*>(u)[t];
    float4 ww;
    ww.x = sp_w(uu.x); ww.y = sp_w(uu.y); ww.z = sp_w(uu.z); ww.w = sp_w(uu.w);
    reinterpret_cast<float4*>(w)[t] = ww;
}

// init (4 elems/thread): rg=rhs, dg, cl arrays + rs0 reduction. Reads precomputed w.
__global__ __launch_bounds__(256) void k_init(const int* __restrict__ idx,
                                              const float* __restrict__ w_all,
                                              const float* __restrict__ x,
                                              float* __restrict__ rg,
                                              float* __restrict__ dg,
                                              float* __restrict__ cl,
                                              float* __restrict__ rs_arr,
                                              int n, int K) {
    int t = blockIdx.x * 256 + threadIdx.x;
    int g = t * 4;
    int b = g / K;
    int k = g - b * K;
    int m = n - 1;
    const float* wb = w_all + (size_t)b * m;
    const float* xb = x + (size_t)b * n;
    int4 i4 = reinterpret_cast<const int4*>(idx)[k / 4];
    int jj[6];
    jj[0] = (k > 0) ? idx[k - 1] : -1000000;
    jj[1] = i4.x; jj[2] = i4.y; jj[3] = i4.z; jj[4] = i4.w;
    jj[5] = (k + 4 < K) ? idx[k + 4] : -1000000;
    float rh[4], dgv[4], clv[4];
    float s0 = 0.f;
    #pragma unroll
    for (int q = 0; q < 4; ++q) {
        int j = jj[q + 1];
        bool la = (jj[q] == j - 1);
        bool ra = (jj[q + 2] == j + 1);
        float wl = 0.f, wr = 0.f;
        if (j >= 1)     { float w = wb[j - 1]; wl = w * w; }
        if (j <= n - 2) { float w = wb[j];     wr = w * w; }
        float rhs = 0.f;
        if (j >= 1 && !la)     rhs += wl * nn(xb[j - 1]);
        if (j <= n - 2 && !ra) rhs += wr * nn(xb[j + 1]);
        rh[q] = rhs; dgv[q] = wl + wr; clv[q] = la ? wl : 0.f;
        s0 += rhs * rhs;
    }
    reinterpret_cast<float4*>(rg)[t] = make_float4(rh[0], rh[1], rh[2], rh[3]);
    reinterpret_cast<float4*>(dg)[t] = make_float4(dgv[0], dgv[1], dgv[2], dgv[3]);
    reinterpret_cast<float4*>(cl)[t] = make_float4(clv[0], clv[1], clv[2], clv[3]);
    float s = blockReduceSum(s0);
    if (threadIdx.x == 0) atomicAdd(&rs_arr[b], s);
}

// Persistent CG: state in registers; per-batch spin barriers (no grid.sync).
__global__ __attribute__((amdgpu_flat_work_group_size(256, 256),
                          amdgpu_waves_per_eu(2, 2)))
void k_cg_pers(
        const float* __restrict__ rg_in, const float* __restrict__ dg_in,
        const float* __restrict__ cl_in, float* __restrict__ v_out,
        float* __restrict__ rs_arr, float* __restrict__ pkp_arr,
        float* __restrict__ pbl, float* __restrict__ pbr,   // [2*grid]
        float* __restrict__ rbl, float* __restrict__ rbr,   // [grid]
        int* __restrict__ arrive, int* __restrict__ release, // [grid], [B*32]
        int K, int B, int total, int nblk) {
    const int blk = blockIdx.x, tid = threadIdx.x;
    const int bpb = K / CHUNK;              // 32 blocks per batch
    const int b = blk / bpb;
    const int bbase = b * bpb;
    const int relIdx = b * 32;              // 128B-padded release slot
    const bool leader = (blk == bbase);
    const bool first_blk = (blk == bbase);
    const bool last_blk  = (blk == bbase + bpb - 1);
    const size_t g0 = (size_t)blk * CHUNK + (size_t)tid * E;

    float vv[E], rcg[E], p[E], kp[E], dgr[E], clr[E + 1];
    #pragma unroll
    for (int q4 = 0; q4 < E / 4; ++q4) {
        float4 r = reinterpret_cast<const float4*>(rg_in)[g0 / 4 + q4];
        float4 d = reinterpret_cast<const float4*>(dg_in)[g0 / 4 + q4];
        float4 c = reinterpret_cast<const float4*>(cl_in)[g0 / 4 + q4];
        rcg[4 * q4 + 0] = r.x; rcg[4 * q4 + 1] = r.y; rcg[4 * q4 + 2] = r.z; rcg[4 * q4 + 3] = r.w;
        dgr[4 * q4 + 0] = d.x; dgr[4 * q4 + 1] = d.y; dgr[4 * q4 + 2] = d.z; dgr[4 * q4 + 3] = d.w;
        clr[4 * q4 + 0] = c.x; clr[4 * q4 + 1] = c.y; clr[4 * q4 + 2] = c.z; clr[4 * q4 + 3] = c.w;
    }
    clr[E] = (g0 + E < (size_t)total) ? cl_in[g0 + E] : 0.f;
    #pragma unroll
    for (int q = 0; q < E; ++q) { vv[q] = 0.f; p[q] = rcg[q]; kp[q] = 0.f; }

    if (tid == 0)         { agent_st(&rbl[blk], rcg[0]);     agent_st(&pbl[blk], p[0]); }
    if (tid == CGBLK - 1) { agent_st(&rbr[blk], rcg[E - 1]); agent_st(&pbr[blk], p[E - 1]); }
    batch_barrier(arrive, release, blk, bbase, bpb, relIdx, 1, leader);

    __shared__ float sLa[CGBLK], sRa[CGBLK];

    for (int it = 0; it < MAX_ITER; ++it) {
        // ---- phase A: p update, halos, Kp, p.Kp ----
        float beta = 0.f;
        if (it > 0)
            beta = agent_ld(&rs_arr[it * B + b]) /
                   (agent_ld(&rs_arr[(it - 1) * B + b]) + 1e-30f);
        #pragma unroll
        for (int q = 0; q < E; ++q) p[q] = rcg[q] + beta * p[q];
        sLa[tid] = p[0]; sRa[tid] = p[E - 1];
        __syncthreads();
        int rslot = (it & 1) * nblk, wslot = ((it + 1) & 1) * nblk;
        float pl, pr;
        if (tid > 0) pl = sRa[tid - 1];
        else pl = first_blk ? 0.f
                            : (agent_ld(&rbr[blk - 1]) + beta * agent_ld(&pbr[rslot + blk - 1]));
        if (tid < CGBLK - 1) pr = sLa[tid + 1];
        else pr = last_blk ? 0.f
                           : (agent_ld(&rbl[blk + 1]) + beta * agent_ld(&pbl[rslot + blk + 1]));
        if (tid == 0)         agent_st(&pbl[wslot + blk], p[0]);
        if (tid == CGBLK - 1) agent_st(&pbr[wslot + blk], p[E - 1]);
        float dot = 0.f;
        #pragma unroll
        for (int q = 0; q < E; ++q) {
            float pm = (q == 0) ? pl : p[q - 1];
            float pp = (q == E - 1) ? pr : p[q + 1];
            kp[q] = dgr[q] * p[q] - clr[q] * pm - clr[q + 1] * pp;
            dot += p[q] * kp[q];
        }
        float d = blockReduceSum(dot);
        if (tid == 0) atomicAdd(&pkp_arr[it * B + b], d);
        batch_barrier(arrive, release, blk, bbase, bpb, relIdx, 2 + 2 * it, leader);

        // ---- phase B: alpha, v/rcg update, ||r||^2 ----
        float alpha = agent_ld(&rs_arr[it * B + b]) /
                      (agent_ld(&pkp_arr[it * B + b]) + 1e-30f);
        float dot2 = 0.f;
        #pragma unroll
        for (int q = 0; q < E; ++q) {
            vv[q] += alpha * p[q];
            rcg[q] -= alpha * kp[q];
            dot2 += rcg[q] * rcg[q];
        }
        float d2 = blockReduceSum(dot2);
        if (tid == 0) {
            atomicAdd(&rs_arr[(it + 1) * B + b], d2);
            agent_st(&rbl[blk], rcg[0]);
        }
        if (tid == CGBLK - 1) agent_st(&rbr[blk], rcg[E - 1]);
        batch_barrier(arrive, release, blk, bbase, bpb, relIdx, 3 + 2 * it, leader);
    }

    #pragma unroll
    for (int q4 = 0; q4 < E / 4; ++q4)
        reinterpret_cast<float4*>(v_out)[g0 / 4 + q4] =
            make_float4(vv[4 * q4], vv[4 * q4 + 1], vv[4 * q4 + 2], vv[4 * q4 + 3]);
}

// ---- fallback multi-kernel CG (round-2, known good) ----
__global__ __launch_bounds__(256) void k_cg_a(const float* __restrict__ rg,
                                              const float* __restrict__ p_old,
                                              float* __restrict__ p_new,
                                              float* __restrict__ kp,
                                              const float* __restrict__ dg,
                                              const float* __restrict__ cl,
                                              const float* __restrict__ rs_arr,
                                              float* __restrict__ pkp_arr,
                                              int iter, int B, int K) {
    int t = blockIdx.x * 256 + threadIdx.x;
    int g = t * 4;
    int total = B * K;
    int b = g / K;
    float beta = (iter == 0) ? 0.f
               : rs_arr[iter * B + b] / (rs_arr[(iter - 1) * B + b] + 1e-30f);
    float4 rc = reinterpret_cast<const float4*>(rg)[t];
    float4 po = reinterpret_cast<const float4*>(p_old)[t];
    float4 dd = reinterpret_cast<const float4*>(dg)[t];
    float4 cc = reinterpret_cast<const float4*>(cl)[t];
    float rcm = (g > 0) ? rg[g - 1] : 0.f;
    float pom = (g > 0) ? p_old[g - 1] : 0.f;
    bool tail = (g + 4 < total);
    float rcp = tail ? rg[g + 4] : 0.f;
    float pop = tail ? p_old[g + 4] : 0.f;
    float ccp = tail ? cl[g + 4] : 0.f;
    float pn[6];
    pn[0] = rcm + beta * pom;
    pn[1] = rc.x + beta * po.x;
    pn[2] = rc.y + beta * po.y;
    pn[3] = rc.z + beta * po.z;
    pn[4] = rc.w + beta * po.w;
    pn[5] = rcp + beta * pop;
    float c[5] = {cc.x, cc.y, cc.z, cc.w, ccp};
    float d4[4] = {dd.x, dd.y, dd.z, dd.w};
    float kv[4];
    float dot = 0.f;
    #pragma unroll
    for (int i = 0; i < 4; ++i) {
        kv[i] = d4[i] * pn[i + 1] - c[i] * pn[i] - c[i + 1] * pn[i + 2];
        dot += pn[i + 1] * kv[i];
    }
    reinterpret_cast<float4*>(p_new)[t] = make_float4(pn[1], pn[2], pn[3], pn[4]);
    reinterpret_cast<float4*>(kp)[t]    = make_float4(kv[0], kv[1], kv[2], kv[3]);
    float s = blockReduceSum(dot);
    if (threadIdx.x == 0) atomicAdd(&pkp_arr[iter * B + b], s);
}

__global__ __launch_bounds__(256) void k_cg_b(float* __restrict__ v,
                                              float* __restrict__ rg,
                                              const float* __restrict__ p_new,
                                              const float* __restrict__ kp,
                                              float* __restrict__ rs_arr,
                                              const float* __restrict__ pkp_arr,
                                              int iter, int B, int K) {
    int t = blockIdx.x * 256 + threadIdx.x;
    int g = t * 4;
    int b = g / K;
    float alpha = rs_arr[iter * B + b] / (pkp_arr[iter * B + b] + 1e-30f);
    float4 pv = reinterpret_cast<const float4*>(p_new)[t];
    float4 kv = reinterpret_cast<const float4*>(kp)[t];
    float4 vv = reinterpret_cast<float4*>(v)[t];
    float4 rv = reinterpret_cast<float4*>(rg)[t];
    vv.x += alpha * pv.x; vv.y += alpha * pv.y; vv.z += alpha * pv.z; vv.w += alpha * pv.w;
    rv.x -= alpha * kv.x; rv.y -= alpha * kv.y; rv.z -= alpha * kv.z; rv.w -= alpha * kv.w;
    reinterpret_cast<float4*>(v)[t]  = vv;
    reinterpret_cast<float4*>(rg)[t] = rv;
    float dot = rv.x * rv.x + rv.y * rv.y + rv.z * rv.z + rv.w * rv.w;
    float s = blockReduceSum(dot);
    if (threadIdx.x == 0) atomicAdd(&rs_arr[(iter + 1) * B + b], s);
}

// final: r = D(x_known + scatter(v)), phi = sum w^2 r^2
__global__ __launch_bounds__(256) void k_final(const float* __restrict__ x,
                                               const float* __restrict__ w_out,
                                               const int* __restrict__ pos,
                                               const float* __restrict__ v,
                                               float* __restrict__ r_out,
                                               float* __restrict__ phi,
                                               int n, int K) {
    int m = n - 1;
    int b = blockIdx.y;
    int i0 = (blockIdx.x * 256 + threadIdx.x) * 4;
    const float* xb = x + (size_t)b * n;
    const float* wb = w_out + (size_t)b * m;
    const float* vb = v + (size_t)b * K;
    float* rb = r_out + (size_t)b * m;
    float sv[5];
    #pragma unroll
    for (int q = 0; q < 5; ++q) {
        int i = i0 + q;
        if (i <= m) {
            int p = pos[i];
            sv[q] = (p >= 0) ? vb[p] : nn(xb[i]);
        } else sv[q] = 0.f;
    }
    float acc = 0.f;
    #pragma unroll
    for (int q = 0; q < 4; ++q) {
        int i = i0 + q;
        if (i < m) {
            float r = sv[q + 1] - sv[q];
            rb[i] = r;
            float w = wb[i];
            acc += w * w * r * r;
        }
    }
    float s = blockReduceSum(acc);
    if (threadIdx.x == 0) atomicAdd(&phi[b], s);
}

extern "C" void kernel_launch(void* const* d_in, const int* in_sizes, int n_in,
                              void* d_out, int out_size, void* d_ws, size_t ws_size,
                              hipStream_t stream) {
    const float* u  = (const float*)d_in[0];  // [B, n-1]
    const float* x  = (const float*)d_in[1];  // [B, n]
    const int* idx  = (const int*)d_in[2];    // [K]

    const int B = 16;
    const int n = in_sizes[1] / B;   // 262144
    const int m = n - 1;             // 262143
    const int K = in_sizes[2];       // 131072
    const int NK = B * K;            // 2097152
    const int GRID = NK / CHUNK;     // 512 blocks

    float* out   = (float*)d_out;
    float* phi   = out;                         // [B]
    float* v_out = out + B;                     // [B,K]
    float* r_out = v_out + (size_t)B * K;       // [B,m]
    float* w_out = r_out + (size_t)B * m;       // [B,m]

    char* ws = (char*)d_ws;
    float* rg  = (float*)ws;      ws += sizeof(float) * (size_t)NK;
    float* dg  = (float*)ws;      ws += sizeof(float) * (size_t)NK;
    float* cl  = (float*)ws;      ws += sizeof(float) * (size_t)NK;
    float* p0f = (float*)ws;      ws += sizeof(float) * (size_t)NK;
    float* p1f = (float*)ws;      ws += sizeof(float) * (size_t)NK;
    float* kpf = (float*)ws;      ws += sizeof(float) * (size_t)NK;
    float* vf  = (float*)ws;      ws += sizeof(float) * (size_t)NK;
    float* rs_arr  = (float*)ws;  ws += sizeof(float) * (MAX_ITER + 1) * B;
    float* pkp_arr = (float*)ws;  ws += sizeof(float) * MAX_ITER * B;
    float* pbl = (float*)ws;      ws += sizeof(float) * 2 * GRID;
    float* pbr = (float*)ws;      ws += sizeof(float) * 2 * GRID;
    float* rbl = (float*)ws;      ws += sizeof(float) * GRID;
    float* rbr = (float*)ws;      ws += sizeof(float) * GRID;
    int*   pos = (int*)ws;        ws += sizeof(int) * (size_t)n;
    int*   arrive  = (int*)ws;    ws += sizeof(int) * GRID;
    int*   release = (int*)ws;    ws += sizeof(int) * B * 32;

    hipMemsetAsync(rs_arr, 0, sizeof(float) * ((MAX_ITER + 1) * B + MAX_ITER * B), stream);
    hipMemsetAsync(pos, 0xFF, sizeof(int) * (size_t)n, stream);  // -1
    hipMemsetAsync(phi, 0, sizeof(float) * B, stream);
    hipMemsetAsync(arrive, 0, sizeof(int) * (GRID + B * 32), stream);

    k_scatter<<<(K + 255) / 256, 256, 0, stream>>>(idx, pos, K);

    int tot4w = (B * m) / 4;
    k_w<<<(tot4w + 255) / 256, 256, 0, stream>>>(u, w_out, tot4w);

    k_init<<<NK / 1024, 256, 0, stream>>>(idx, w_out, x, rg, dg, cl, rs_arr, n, K);

    int K_ = K, B_ = B, total_ = NK, nblk_ = GRID;
    void* args[] = {(void*)&rg, (void*)&dg, (void*)&cl, (void*)&v_out,
                    (void*)&rs_arr, (void*)&pkp_arr,
                    (void*)&pbl, (void*)&pbr, (void*)&rbl, (void*)&rbr,
                    (void*)&arrive, (void*)&release,
                    (void*)&K_, (void*)&B_, (void*)&total_, (void*)&nblk_};
    hipError_t cerr = hipLaunchCooperativeKernel((const void*)k_cg_pers, dim3(GRID),
                                                 dim3(CGBLK), args, 0, stream);
    const float* vsrc = v_out;
    if (cerr != hipSuccess) {
        // fallback: known-good multi-kernel CG loop
        hipMemsetAsync(vf, 0, sizeof(float) * (size_t)NK, stream);
        for (int it = 0; it < MAX_ITER; ++it) {
            const float* po = (it == 0) ? rg : ((it & 1) ? p0f : p1f);
            float* pnw = (it & 1) ? p1f : p0f;
            k_cg_a<<<NK / 1024, 256, 0, stream>>>(rg, po, pnw, kpf, dg, cl,
                                                  rs_arr, pkp_arr, it, B, K);
            k_cg_b<<<NK / 1024, 256, 0, stream>>>(vf, rg, pnw, kpf,
                                                  rs_arr, pkp_arr, it, B, K);
        }
        hipMemcpyAsync(v_out, vf, sizeof(float) * (size_t)NK, hipMemcpyDeviceToDevice, stream);
        vsrc = vf;
    }

    k_final<<<dim3((m + 1023) / 1024, B), 256, 0, stream>>>(x, w_out, pos, vsrc, r_out, phi, n, K);
}

// Round 6
// 992.502 us; speedup vs baseline: 2.3744x; 1.3860x over previous
//
#include <hip/hip_runtime.h>
#include <math.h>

#define MAX_ITER 20
#define EPS_W 1e-3f
#define CLAMP_MIN 1e-4f
#define CLAMP_MAX 1e4f

#define E 16
#define CGBLK 256
#define CHUNK (E * CGBLK)  // 4096 elements per block; bpb = K/CHUNK = 32

__device__ __forceinline__ float sp_w(float u) {
    float sp = fmaxf(u, 0.f) + log1pf(expf(-fabsf(u)));
    float w = sp + EPS_W;
    return fminf(fmaxf(w, CLAMP_MIN), CLAMP_MAX);
}
__device__ __forceinline__ float nn(float x) { return (x == x) ? x : 0.f; }

__device__ __forceinline__ float agent_ld(const float* p) {
    return __hip_atomic_load(p, __ATOMIC_RELAXED, __HIP_MEMORY_SCOPE_AGENT);
}
__device__ __forceinline__ void agent_st(float* p, float v) {
    __hip_atomic_store(p, v, __ATOMIC_RELAXED, __HIP_MEMORY_SCOPE_AGENT);
}
__device__ __forceinline__ unsigned long long ld64(const unsigned long long* p, bool acq) {
    return acq ? __hip_atomic_load(p, __ATOMIC_ACQUIRE, __HIP_MEMORY_SCOPE_AGENT)
               : __hip_atomic_load(p, __ATOMIC_RELAXED, __HIP_MEMORY_SCOPE_AGENT);
}
__device__ __forceinline__ void st64(unsigned long long* p, unsigned long long v) {
    __hip_atomic_store(p, v, __ATOMIC_RELAXED, __HIP_MEMORY_SCOPE_AGENT);
}

// result valid on threadIdx.x == 0 only; block must be 256 threads (4 waves)
__device__ __forceinline__ float blockReduceSum(float v) {
    #pragma unroll
    for (int off = 32; off > 0; off >>= 1) v += __shfl_down(v, off, 64);
    __shared__ float smem[4];
    int lane = threadIdx.x & 63, wid = threadIdx.x >> 6;
    if (lane == 0) smem[wid] = v;
    __syncthreads();
    float r = 0.f;
    if (threadIdx.x == 0) r = smem[0] + smem[1] + smem[2] + smem[3];
    return r;
}

// Fused per-batch reduction + barrier. Every block publishes {gen, blocksum} to
// slotA[blk]; the batch leader polls its 32 slots (one lane each, RELAXED with
// periodic ACQUIRE), wave-reduces, publishes {gen, total} to slotR[relIdx];
// waiters poll that one word. Returns batch-wide sum to all threads.
// Assumes bpb <= 32. Slots are zeroed per call; gen starts at 1.
__device__ float round_sum(float partial, unsigned gen,
                           unsigned long long* __restrict__ slotA,
                           unsigned long long* __restrict__ slotR,
                           int blk, int bbase, int bpb, int relIdx, bool leader) {
    __shared__ float bsum;
    float bs = blockReduceSum(partial);          // valid on tid 0
    // drain this thread's prior global (halo) stores before anyone publishes
    __builtin_amdgcn_fence(__ATOMIC_RELEASE, "agent");
    __syncthreads();
    const int tid = threadIdx.x;
    if (tid == 0)
        st64(&slotA[blk], ((unsigned long long)gen << 32) | __float_as_uint(bs));
    if (leader) {
        float lp = 0.f;
        if (tid < bpb) {
            unsigned long long v; int s = 0;
            for (;;) {
                v = ld64(&slotA[bbase + tid], false);
                if ((unsigned)(v >> 32) >= gen) break;
                if ((++s & 255) == 0) {
                    v = ld64(&slotA[bbase + tid], true);
                    if ((unsigned)(v >> 32) >= gen) break;
                }
                __builtin_amdgcn_s_sleep(1);
            }
            lp = __uint_as_float((unsigned)v);
        }
        #pragma unroll
        for (int off = 16; off > 0; off >>= 1) lp += __shfl_down(lp, off, 32);
        if (tid == 0) {
            __builtin_amdgcn_fence(__ATOMIC_ACQUIRE, "agent");
            st64(&slotR[relIdx], ((unsigned long long)gen << 32) | __float_as_uint(lp));
            bsum = lp;
        }
    } else {
        if (tid == 0) {
            unsigned long long v; int s = 0;
            for (;;) {
                v = ld64(&slotR[relIdx], false);
                if ((unsigned)(v >> 32) >= gen) break;
                if ((++s & 255) == 0) {
                    v = ld64(&slotR[relIdx], true);
                    if ((unsigned)(v >> 32) >= gen) break;
                }
                __builtin_amdgcn_s_sleep(1);
            }
            __builtin_amdgcn_fence(__ATOMIC_ACQUIRE, "agent");
            bsum = __uint_as_float((unsigned)v);
        }
    }
    __syncthreads();
    return bsum;
}

__global__ __launch_bounds__(256) void k_scatter(const int* __restrict__ idx,
                                                 int* __restrict__ pos, int K) {
    int k = blockIdx.x * 256 + threadIdx.x;
    if (k < K) pos[idx[k]] = k;
}

__global__ __launch_bounds__(256) void k_w(const float* __restrict__ u,
                                           float* __restrict__ w, int total4) {
    int t = blockIdx.x * 256 + threadIdx.x;
    if (t >= total4) return;
    float4 uu = reinterpret_cast<const float4*>(u)[t];
    float4 ww;
    ww.x = sp_w(uu.x); ww.y = sp_w(uu.y); ww.z = sp_w(uu.z); ww.w = sp_w(uu.w);
    reinterpret_cast<float4*>(w)[t] = ww;
}

// Persistent CG: init + 20 iterations, all state in registers.
// (Kp)[k] = dg[k]*p[k] - cl[k]*p[k-1] - cl[k+1]*p[k+1]
__global__ __attribute__((amdgpu_flat_work_group_size(256, 256),
                          amdgpu_waves_per_eu(2, 2)))
void k_cg_pers(
        const int* __restrict__ idx, const float* __restrict__ w_all,
        const float* __restrict__ x, float* __restrict__ v_out,
        unsigned long long* __restrict__ slotA,   // [nblk]
        unsigned long long* __restrict__ slotR,   // [B*16], 128B-padded per batch
        float* __restrict__ pbl, float* __restrict__ pbr,   // [2*nblk] parity dbuf
        float* __restrict__ rbl, float* __restrict__ rbr,   // [nblk]
        int n, int K, int B, int nblk) {
    const int blk = blockIdx.x, tid = threadIdx.x;
    const int bpb = K / CHUNK;                 // 32 blocks per batch
    const int b = blk / bpb;
    const int bbase = b * bpb;
    const int relIdx = b * 16;
    const bool leader = (blk == bbase);
    const bool first_blk = (blk == bbase);
    const bool last_blk  = (blk == bbase + bpb - 1);
    const int k0 = (blk - bbase) * CHUNK + tid * E;
    const int m = n - 1;
    const float* wb = w_all + (size_t)b * m;
    const float* xb = x + (size_t)b * n;

    // ---------- init: build dg, cl, rhs in registers ----------
    int jj[E + 2];
    #pragma unroll
    for (int t = 0; t < E + 2; ++t) {
        int k = k0 - 1 + t;
        jj[t] = (k >= 0 && k < K) ? idx[k] : -1000000;
    }
    float vv[E], rcg[E], p[E], kp[E], dgr[E], clr[E + 1];
    float s0 = 0.f;
    #pragma unroll
    for (int q = 0; q < E; ++q) {
        int j = jj[q + 1];
        bool la = (jj[q] == j - 1);
        bool ra = (jj[q + 2] == j + 1);
        float wl = 0.f, wr = 0.f;
        if (j >= 1)     { float w = wb[j - 1]; wl = w * w; }
        if (j <= n - 2) { float w = wb[j];     wr = w * w; }
        float rhs = 0.f;
        if (j >= 1 && !la)     rhs += wl * nn(xb[j - 1]);
        if (j <= n - 2 && !ra) rhs += wr * nn(xb[j + 1]);
        vv[q] = 0.f; rcg[q] = rhs; p[q] = rhs; kp[q] = 0.f;
        dgr[q] = wl + wr;
        clr[q] = la ? wl : 0.f;
        s0 += rhs * rhs;
    }
    {   // clr[E] = left coupling of element k0+E (first elem of next thread)
        float cl8 = 0.f;
        int j8 = jj[E + 1];
        if ((k0 + E) < K && jj[E] == j8 - 1) { float w = wb[j8 - 1]; cl8 = w * w; }
        clr[E] = cl8;
    }
    if (tid == 0)         { agent_st(&rbl[blk], rcg[0]);     agent_st(&pbl[blk], p[0]); }
    if (tid == CGBLK - 1) { agent_st(&rbr[blk], rcg[E - 1]); agent_st(&pbr[blk], p[E - 1]); }

    float rs_prev = 1.f;
    float rs_cur = round_sum(s0, 1u, slotA, slotR, blk, bbase, bpb, relIdx, leader);

    __shared__ float sLa[CGBLK], sRa[CGBLK];

    for (int it = 0; it < MAX_ITER; ++it) {
        // ---- phase A: p update, halos, Kp, p.Kp ----
        float beta = (it > 0) ? rs_cur / (rs_prev + 1e-30f) : 0.f;
        #pragma unroll
        for (int q = 0; q < E; ++q) p[q] = rcg[q] + beta * p[q];
        sLa[tid] = p[0]; sRa[tid] = p[E - 1];
        __syncthreads();
        int rslot = (it & 1) * nblk, wslot = ((it + 1) & 1) * nblk;
        float pl, pr;
        if (tid > 0) pl = sRa[tid - 1];
        else pl = first_blk ? 0.f
                            : (agent_ld(&rbr[blk - 1]) + beta * agent_ld(&pbr[rslot + blk - 1]));
        if (tid < CGBLK - 1) pr = sLa[tid + 1];
        else pr = last_blk ? 0.f
                           : (agent_ld(&rbl[blk + 1]) + beta * agent_ld(&pbl[rslot + blk + 1]));
        if (tid == 0)         agent_st(&pbl[wslot + blk], p[0]);
        if (tid == CGBLK - 1) agent_st(&pbr[wslot + blk], p[E - 1]);
        float dot = 0.f;
        #pragma unroll
        for (int q = 0; q < E; ++q) {
            float pm = (q == 0) ? pl : p[q - 1];
            float pp = (q == E - 1) ? pr : p[q + 1];
            kp[q] = dgr[q] * p[q] - clr[q] * pm - clr[q + 1] * pp;
            dot += p[q] * kp[q];
        }
        float pkp = round_sum(dot, 2u + 2u * it, slotA, slotR, blk, bbase, bpb, relIdx, leader);

        // ---- phase B: alpha, v/rcg update, ||r||^2 ----
        float alpha = rs_cur / (pkp + 1e-30f);
        float dot2 = 0.f;
        #pragma unroll
        for (int q = 0; q < E; ++q) {
            vv[q] += alpha * p[q];
            rcg[q] -= alpha * kp[q];
            dot2 += rcg[q] * rcg[q];
        }
        if (tid == 0)         agent_st(&rbl[blk], rcg[0]);
        if (tid == CGBLK - 1) agent_st(&rbr[blk], rcg[E - 1]);
        float rs_new = round_sum(dot2, 3u + 2u * it, slotA, slotR, blk, bbase, bpb, relIdx, leader);
        rs_prev = rs_cur; rs_cur = rs_new;
    }

    float* vb = v_out + (size_t)b * K + (size_t)(blk - bbase) * CHUNK + (size_t)tid * E;
    #pragma unroll
    for (int q4 = 0; q4 < E / 4; ++q4)
        reinterpret_cast<float4*>(vb)[q4] =
            make_float4(vv[4 * q4], vv[4 * q4 + 1], vv[4 * q4 + 2], vv[4 * q4 + 3]);
}

// ---- fallback path kernels (only used if cooperative launch fails) ----
__global__ __launch_bounds__(256) void k_init(const int* __restrict__ idx,
                                              const float* __restrict__ w_all,
                                              const float* __restrict__ x,
                                              float* __restrict__ rg,
                                              float* __restrict__ dg,
                                              float* __restrict__ cl,
                                              float* __restrict__ rs_arr,
                                              int n, int K) {
    int t = blockIdx.x * 256 + threadIdx.x;
    int g = t * 4;
    int b = g / K;
    int k = g - b * K;
    int m = n - 1;
    const float* wb = w_all + (size_t)b * m;
    const float* xb = x + (size_t)b * n;
    int4 i4 = reinterpret_cast<const int4*>(idx)[k / 4];
    int jj[6];
    jj[0] = (k > 0) ? idx[k - 1] : -1000000;
    jj[1] = i4.x; jj[2] = i4.y; jj[3] = i4.z; jj[4] = i4.w;
    jj[5] = (k + 4 < K) ? idx[k + 4] : -1000000;
    float rh[4], dgv[4], clv[4];
    float s0 = 0.f;
    #pragma unroll
    for (int q = 0; q < 4; ++q) {
        int j = jj[q + 1];
        bool la = (jj[q] == j - 1);
        bool ra = (jj[q + 2] == j + 1);
        float wl = 0.f, wr = 0.f;
        if (j >= 1)     { float w = wb[j - 1]; wl = w * w; }
        if (j <= n - 2) { float w = wb[j];     wr = w * w; }
        float rhs = 0.f;
        if (j >= 1 && !la)     rhs += wl * nn(xb[j - 1]);
        if (j <= n - 2 && !ra) rhs += wr * nn(xb[j + 1]);
        rh[q] = rhs; dgv[q] = wl + wr; clv[q] = la ? wl : 0.f;
        s0 += rhs * rhs;
    }
    reinterpret_cast<float4*>(rg)[t] = make_float4(rh[0], rh[1], rh[2], rh[3]);
    reinterpret_cast<float4*>(dg)[t] = make_float4(dgv[0], dgv[1], dgv[2], dgv[3]);
    reinterpret_cast<float4*>(cl)[t] = make_float4(clv[0], clv[1], clv[2], clv[3]);
    float s = blockReduceSum(s0);
    if (threadIdx.x == 0) atomicAdd(&rs_arr[b], s);
}

__global__ __launch_bounds__(256) void k_cg_a(const float* __restrict__ rg,
                                              const float* __restrict__ p_old,
                                              float* __restrict__ p_new,
                                              float* __restrict__ kp,
                                              const float* __restrict__ dg,
                                              const float* __restrict__ cl,
                                              const float* __restrict__ rs_arr,
                                              float* __restrict__ pkp_arr,
                                              int iter, int B, int K) {
    int t = blockIdx.x * 256 + threadIdx.x;
    int g = t * 4;
    int total = B * K;
    int b = g / K;
    float beta = (iter == 0) ? 0.f
               : rs_arr[iter * B + b] / (rs_arr[(iter - 1) * B + b] + 1e-30f);
    float4 rc = reinterpret_cast<const float4*>(rg)[t];
    float4 po = reinterpret_cast<const float4*>(p_old)[t];
    float4 dd = reinterpret_cast<const float4*>(dg)[t];
    float4 cc = reinterpret_cast<const float4*>(cl)[t];
    float rcm = (g > 0) ? rg[g - 1] : 0.f;
    float pom = (g > 0) ? p_old[g - 1] : 0.f;
    bool tail = (g + 4 < total);
    float rcp = tail ? rg[g + 4] : 0.f;
    float pop = tail ? p_old[g + 4] : 0.f;
    float ccp = tail ? cl[g + 4] : 0.f;
    float pn[6];
    pn[0] = rcm + beta * pom;
    pn[1] = rc.x + beta * po.x;
    pn[2] = rc.y + beta * po.y;
    pn[3] = rc.z + beta * po.z;
    pn[4] = rc.w + beta * po.w;
    pn[5] = rcp + beta * pop;
    float c[5] = {cc.x, cc.y, cc.z, cc.w, ccp};
    float d4[4] = {dd.x, dd.y, dd.z, dd.w};
    float kv[4];
    float dot = 0.f;
    #pragma unroll
    for (int i = 0; i < 4; ++i) {
        kv[i] = d4[i] * pn[i + 1] - c[i] * pn[i] - c[i + 1] * pn[i + 2];
        dot += pn[i + 1] * kv[i];
    }
    reinterpret_cast<float4*>(p_new)[t] = make_float4(pn[1], pn[2], pn[3], pn[4]);
    reinterpret_cast<float4*>(kp)[t]    = make_float4(kv[0], kv[1], kv[2], kv[3]);
    float s = blockReduceSum(dot);
    if (threadIdx.x == 0) atomicAdd(&pkp_arr[iter * B + b], s);
}

__global__ __launch_bounds__(256) void k_cg_b(float* __restrict__ v,
                                              float* __restrict__ rg,
                                              const float* __restrict__ p_new,
                                              const float* __restrict__ kp,
                                              float* __restrict__ rs_arr,
                                              const float* __restrict__ pkp_arr,
                                              int iter, int B, int K) {
    int t = blockIdx.x * 256 + threadIdx.x;
    int g = t * 4;
    int b = g / K;
    float alpha = rs_arr[iter * B + b] / (pkp_arr[iter * B + b] + 1e-30f);
    float4 pv = reinterpret_cast<const float4*>(p_new)[t];
    float4 kv = reinterpret_cast<const float4*>(kp)[t];
    float4 vv = reinterpret_cast<float4*>(v)[t];
    float4 rv = reinterpret_cast<float4*>(rg)[t];
    vv.x += alpha * pv.x; vv.y += alpha * pv.y; vv.z += alpha * pv.z; vv.w += alpha * pv.w;
    rv.x -= alpha * kv.x; rv.y -= alpha * kv.y; rv.z -= alpha * kv.z; rv.w -= alpha * kv.w;
    reinterpret_cast<float4*>(v)[t]  = vv;
    reinterpret_cast<float4*>(rg)[t] = rv;
    float dot = rv.x * rv.x + rv.y * rv.y + rv.z * rv.z + rv.w * rv.w;
    float s = blockReduceSum(dot);
    if (threadIdx.x == 0) atomicAdd(&rs_arr[(iter + 1) * B + b], s);
}

// final: r = D(x_known + scatter(v)), phi = sum w^2 r^2
__global__ __launch_bounds__(256) void k_final(const float* __restrict__ x,
                                               const float* __restrict__ w_out,
                                               const int* __restrict__ pos,
                                               const float* __restrict__ v,
                                               float* __restrict__ r_out,
                                               float* __restrict__ phi,
                                               int n, int K) {
    int m = n - 1;
    int b = blockIdx.y;
    int i0 = (blockIdx.x * 256 + threadIdx.x) * 4;
    const float* xb = x + (size_t)b * n;
    const float* wb = w_out + (size_t)b * m;
    const float* vb = v + (size_t)b * K;
    float* rb = r_out + (size_t)b * m;
    float sv[5];
    #pragma unroll
    for (int q = 0; q < 5; ++q) {
        int i = i0 + q;
        if (i <= m) {
            int p = pos[i];
            sv[q] = (p >= 0) ? vb[p] : nn(xb[i]);
        } else sv[q] = 0.f;
    }
    float acc = 0.f;
    #pragma unroll
    for (int q = 0; q < 4; ++q) {
        int i = i0 + q;
        if (i < m) {
            float r = sv[q + 1] - sv[q];
            rb[i] = r;
            float w = wb[i];
            acc += w * w * r * r;
        }
    }
    float s = blockReduceSum(acc);
    if (threadIdx.x == 0) atomicAdd(&phi[b], s);
}

extern "C" void kernel_launch(void* const* d_in, const int* in_sizes, int n_in,
                              void* d_out, int out_size, void* d_ws, size_t ws_size,
                              hipStream_t stream) {
    const float* u  = (const float*)d_in[0];  // [B, n-1]
    const float* x  = (const float*)d_in[1];  // [B, n]
    const int* idx  = (const int*)d_in[2];    // [K]

    const int B = 16;
    const int n = in_sizes[1] / B;   // 262144
    const int m = n - 1;             // 262143
    const int K = in_sizes[2];       // 131072
    const int NK = B * K;            // 2097152
    const int GRID = NK / CHUNK;     // 512 blocks

    float* out   = (float*)d_out;
    float* phi   = out;                         // [B]
    float* v_out = out + B;                     // [B,K]
    float* r_out = v_out + (size_t)B * K;       // [B,m]
    float* w_out = r_out + (size_t)B * m;       // [B,m]

    char* ws = (char*)d_ws;
    float* rg  = (float*)ws;      ws += sizeof(float) * (size_t)NK;   // fallback only
    float* dg  = (float*)ws;      ws += sizeof(float) * (size_t)NK;
    float* cl  = (float*)ws;      ws += sizeof(float) * (size_t)NK;
    float* p0f = (float*)ws;      ws += sizeof(float) * (size_t)NK;
    float* p1f = (float*)ws;      ws += sizeof(float) * (size_t)NK;
    float* kpf = (float*)ws;      ws += sizeof(float) * (size_t)NK;
    float* vf  = (float*)ws;      ws += sizeof(float) * (size_t)NK;
    float* rs_arr  = (float*)ws;  ws += sizeof(float) * (MAX_ITER + 1) * B;
    float* pkp_arr = (float*)ws;  ws += sizeof(float) * MAX_ITER * B;
    float* pbl = (float*)ws;      ws += sizeof(float) * 2 * GRID;
    float* pbr = (float*)ws;      ws += sizeof(float) * 2 * GRID;
    float* rbl = (float*)ws;      ws += sizeof(float) * GRID;
    float* rbr = (float*)ws;      ws += sizeof(float) * GRID;
    int*   pos = (int*)ws;        ws += sizeof(int) * (size_t)n;
    unsigned long long* slotA = (unsigned long long*)ws;  ws += sizeof(unsigned long long) * GRID;
    unsigned long long* slotR = (unsigned long long*)ws;  ws += sizeof(unsigned long long) * B * 16;

    hipMemsetAsync(rs_arr, 0, sizeof(float) * ((MAX_ITER + 1) * B + MAX_ITER * B), stream);
    hipMemsetAsync(pos, 0xFF, sizeof(int) * (size_t)n, stream);  // -1
    hipMemsetAsync(phi, 0, sizeof(float) * B, stream);
    hipMemsetAsync(slotA, 0, sizeof(unsigned long long) * (GRID + B * 16), stream);

    k_scatter<<<(K + 255) / 256, 256, 0, stream>>>(idx, pos, K);

    int tot4w = (B * m) / 4;
    k_w<<<(tot4w + 255) / 256, 256, 0, stream>>>(u, w_out, tot4w);

    int n_ = n, K_ = K, B_ = B, nblk_ = GRID;
    void* args[] = {(void*)&idx, (void*)&w_out, (void*)&x, (void*)&v_out,
                    (void*)&slotA, (void*)&slotR,
                    (void*)&pbl, (void*)&pbr, (void*)&rbl, (void*)&rbr,
                    (void*)&n_, (void*)&K_, (void*)&B_, (void*)&nblk_};
    hipError_t cerr = hipLaunchCooperativeKernel((const void*)k_cg_pers, dim3(GRID),
                                                 dim3(CGBLK), args, 0, stream);
    const float* vsrc = v_out;
    if (cerr != hipSuccess) {
        // fallback: known-good multi-kernel CG loop
        k_init<<<NK / 1024, 256, 0, stream>>>(idx, w_out, x, rg, dg, cl, rs_arr, n, K);
        hipMemsetAsync(vf, 0, sizeof(float) * (size_t)NK, stream);
        for (int it = 0; it < MAX_ITER; ++it) {
            const float* po = (it == 0) ? rg : ((it & 1) ? p0f : p1f);
            float* pnw = (it & 1) ? p1f : p0f;
            k_cg_a<<<NK / 1024, 256, 0, stream>>>(rg, po, pnw, kpf, dg, cl,
                                                  rs_arr, pkp_arr, it, B, K);
            k_cg_b<<<NK / 1024, 256, 0, stream>>>(vf, rg, pnw, kpf,
                                                  rs_arr, pkp_arr, it, B, K);
        }
        hipMemcpyAsync(v_out, vf, sizeof(float) * (size_t)NK, hipMemcpyDeviceToDevice, stream);
        vsrc = vf;
    }

    k_final<<<dim3((m + 1023) / 1024, B), 256, 0, stream>>>(x, w_out, pos, vsrc, r_out, phi, n, K);
}